// Round 7
// baseline (313.609 us; speedup 1.0000x reference)
//
#include <hip/hip_runtime.h>
#include <hip/hip_bf16.h>
#include <stdint.h>

#define N_ROWS 8192
#define DIM 1024
#define NUM_CLS 200
#define NTT 64                    // 128-row tiles per dimension
#define TILES (NTT * (NTT + 1) / 2)   // 2080 upper-tri tiles
#define GRIDB 768                 // persistent blocks (3 per CU)
#define CHUNK (TILES / 8)         // 260 tiles per XCD
#define BSTR (GRIDB / 8)          // 96 blocks per XCD

typedef __attribute__((ext_vector_type(8))) short bf16x8;
typedef __attribute__((ext_vector_type(4))) float f32x4;

__device__ __forceinline__ ushort f2bf(float f) {
    __hip_bfloat16 h = __float2bfloat16(f);
    return *reinterpret_cast<ushort*>(&h);
}

// ---------- Kernel 1: row L2-normalize, cast to bf16 (wave per row) ----------
__global__ __launch_bounds__(256) void normalize_kernel(const float* __restrict__ z,
                                                        ushort* __restrict__ zn) {
    const int row = blockIdx.x * 4 + (threadIdx.x >> 6);
    const int lane = threadIdx.x & 63;
    const float4 v = reinterpret_cast<const float4*>(z + (size_t)row * DIM)[lane];
    float ss = v.x * v.x + v.y * v.y + v.z * v.z + v.w * v.w;
    #pragma unroll
    for (int off = 1; off < 64; off <<= 1) ss += __shfl_xor(ss, off);
    const float inv = 1.0f / fmaxf(sqrtf(ss), 1e-8f);
    ushort4 o;
    o.x = f2bf(v.x * inv);
    o.y = f2bf(v.y * inv);
    o.z = f2bf(v.z * inv);
    o.w = f2bf(v.w * inv);
    reinterpret_cast<ushort4*>(zn + (size_t)row * DIM)[lane] = o;
}

// ---------- Kernel 2: fused Gram + exp + masked row sums ----------
// 128x128 tile, BK=64, 4 waves (2x2), single-buffered 33KB LDS -> 3 blocks/CU
// (reg-bound; __launch_bounds__(256,3) pins it). Both-sides LDS swizzle kills
// the 23-31% bank-conflict tax of r1/r3. Persistent blocks: 768 blocks walk
// an XCD-chunked triangular worklist (260 contiguous tri-tiles per XCD).
__global__ __launch_bounds__(256, 3) void gram_kernel(const ushort* __restrict__ zn,
                                                      const int* __restrict__ labels,
                                                      float* __restrict__ row_same,
                                                      float* __restrict__ row_diff) {
    __shared__ ushort sA[128 * 64];   // 16 KB, rows of 8 x 16B slots, swizzled
    __shared__ ushort sB[128 * 64];   // 16 KB
    __shared__ int labR[128], labC[128];

    const int t = threadIdx.x;
    const int lane = t & 63, wv = t >> 6;   // 4 waves
    const int wr = wv >> 1, wc = wv & 1;    // 2 x 2 wave grid
    const int lrow = lane & 15, lgrp = lane >> 4;
    const int xcd = blockIdx.x & 7;
    const int sub = blockIdx.x >> 3;

    // Hoisted stage geometry: thread t covers chunks c = t + 256*i (16B each).
    // LDS dest linear at chunk c; global source slot inverse-swizzled:
    // physical slot sp holds global slot (sp - r - (r>>3)) & 7   [rule #21]
    int gOff[4];          // element offset within a panel
    ushort* lA[4]; ushort* lB[4];
    #pragma unroll
    for (int i = 0; i < 4; i++) {
        const int c = i * 256 + t;
        const int r = c >> 3, sp = c & 7;
        const int s = (sp - r - (r >> 3)) & 7;
        gOff[i] = r * DIM + s * 8;
        lA[i] = &sA[c * 8];
        lB[i] = &sB[c * 8];
    }

    for (int w = xcd * CHUNK + sub; w < (xcd + 1) * CHUNK; w += BSTR) {
        // triangular decode (row-major upper-tri incl. diagonal)
        int rem = w, bi = 0, len = NTT;
        while (rem >= len) { rem -= len; ++bi; --len; }
        const int bj = bi + rem;
        const bool diag = (bi == bj);
        const int r0 = bi * 128, c0 = bj * 128;

        __syncthreads();   // prior tile's epilogue label-reads done
        if (t < 128) labR[t] = labels[r0 + t];
        else labC[t - 128] = labels[c0 + (t - 128)];

        f32x4 acc[4][4];
        #pragma unroll
        for (int m = 0; m < 4; m++)
            #pragma unroll
            for (int n = 0; n < 4; n++) acc[m][n] = (f32x4){0.f, 0.f, 0.f, 0.f};

        const ushort* pa[4];
        const ushort* pb[4];
        #pragma unroll
        for (int i = 0; i < 4; i++) {
            pa[i] = zn + (size_t)r0 * DIM + gOff[i];
            pb[i] = zn + (size_t)c0 * DIM + gOff[i];
        }

        for (int it = 0; it < DIM / 64; ++it) {
            #pragma unroll
            for (int i = 0; i < 4; i++) {
                __builtin_amdgcn_global_load_lds(
                    (const __attribute__((address_space(1))) uint32_t*)pa[i],
                    (__attribute__((address_space(3))) uint32_t*)lA[i], 16, 0, 0);
                __builtin_amdgcn_global_load_lds(
                    (const __attribute__((address_space(1))) uint32_t*)pb[i],
                    (__attribute__((address_space(3))) uint32_t*)lB[i], 16, 0, 0);
                pa[i] += 64; pb[i] += 64;
            }
            __syncthreads();   // loads landed (vmcnt0) + all waves ready

            bf16x8 a[4][2], b[4][2];
            #pragma unroll
            for (int m = 0; m < 4; m++) {
                const int Ra = wr * 64 + m * 16 + lrow;
                const int Rb = wc * 64 + m * 16 + lrow;
                #pragma unroll
                for (int ks = 0; ks < 2; ks++) {
                    const int spa = (ks * 4 + lgrp + Ra + (Ra >> 3)) & 7;
                    const int spb = (ks * 4 + lgrp + Rb + (Rb >> 3)) & 7;
                    a[m][ks] = *reinterpret_cast<const bf16x8*>(&sA[Ra * 64 + spa * 8]);
                    b[m][ks] = *reinterpret_cast<const bf16x8*>(&sB[Rb * 64 + spb * 8]);
                }
            }
            __builtin_amdgcn_s_setprio(1);
            #pragma unroll
            for (int ks = 0; ks < 2; ks++)
                #pragma unroll
                for (int m = 0; m < 4; m++)
                    #pragma unroll
                    for (int n = 0; n < 4; n++)
                        acc[m][n] = __builtin_amdgcn_mfma_f32_16x16x32_bf16(
                            a[m][ks], b[n][ks], acc[m][n], 0, 0, 0);
            __builtin_amdgcn_s_setprio(0);
            __syncthreads();   // reads done before next stage overwrites
        }

        // ---- Epilogue. C/D: col = lane&15, row = lgrp*4 + q  [m89] ----
        float cs[4] = {0.f, 0.f, 0.f, 0.f}, cd[4] = {0.f, 0.f, 0.f, 0.f};
        #pragma unroll
        for (int m = 0; m < 4; m++) {
            #pragma unroll
            for (int q = 0; q < 4; q++) {
                const int ii = wr * 64 + m * 16 + lgrp * 4 + q;
                const int li = labR[ii];
                float vs = 0.f, vd = 0.f;
                #pragma unroll
                for (int n = 0; n < 4; n++) {
                    const int jj = wc * 64 + n * 16 + lrow;
                    const float e = __expf(acc[m][n][q]);
                    const bool same = (li == labC[jj]);
                    if (!diag || ii != jj) {
                        if (same) { vs += e; if (!diag) cs[n] += e; }
                        else      { vd += e; if (!diag) cd[n] += e; }
                    }
                }
                #pragma unroll
                for (int off = 1; off < 16; off <<= 1) {
                    vs += __shfl_xor(vs, off);
                    vd += __shfl_xor(vd, off);
                }
                if (lrow == 0) {
                    atomicAdd(&row_same[r0 + ii], vs);
                    atomicAdd(&row_diff[r0 + ii], vd);
                }
            }
        }
        if (!diag) {
            #pragma unroll
            for (int n = 0; n < 4; n++) {
                float vs = cs[n], vd = cd[n];
                vs += __shfl_xor(vs, 16); vd += __shfl_xor(vd, 16);
                vs += __shfl_xor(vs, 32); vd += __shfl_xor(vd, 32);
                if (lane < 16) {
                    const int j = c0 + wc * 64 + n * 16 + lane;
                    atomicAdd(&row_same[j], vs);
                    atomicAdd(&row_diff[j], vd);
                }
            }
        }
    }
}

// ---------- Kernel 3a: per-block class partial sums ----------
__global__ __launch_bounds__(256) void class_sum_kernel(const int* __restrict__ labels,
                                                        const float* __restrict__ row_same,
                                                        const float* __restrict__ row_diff,
                                                        float* __restrict__ cls_same,
                                                        float* __restrict__ cls_diff,
                                                        int* __restrict__ cls_cnt) {
    __shared__ float ls[NUM_CLS], ld_[NUM_CLS];
    __shared__ int lc[NUM_CLS];
    const int t = threadIdx.x;
    for (int c = t; c < NUM_CLS; c += 256) { ls[c] = 0.f; ld_[c] = 0.f; lc[c] = 0; }
    __syncthreads();
    const int r = blockIdx.x * 256 + t;
    if (r < N_ROWS) {
        const int l = labels[r];
        atomicAdd(&ls[l], row_same[r]);
        atomicAdd(&ld_[l], row_diff[r]);
        atomicAdd(&lc[l], 1);
    }
    __syncthreads();
    for (int c = t; c < NUM_CLS; c += 256) {
        if (lc[c] > 0) {
            atomicAdd(&cls_same[c], ls[c]);
            atomicAdd(&cls_diff[c], ld_[c]);
            atomicAdd(&cls_cnt[c], lc[c]);
        }
    }
}

// ---------- Kernel 3b: final scalar ----------
__global__ __launch_bounds__(256) void final_kernel(const float* __restrict__ cls_same,
                                                    const float* __restrict__ cls_diff,
                                                    const int* __restrict__ cls_cnt,
                                                    float* __restrict__ out) {
    const int t = threadIdx.x;
    float p = 0.f;
    if (t < NUM_CLS && cls_cnt[t] > 0) p = logf(cls_same[t] / cls_diff[t]);
    #pragma unroll
    for (int off = 1; off < 64; off <<= 1) p += __shfl_xor(p, off);
    __shared__ float wsum[4];
    if ((t & 63) == 0) wsum[t >> 6] = p;
    __syncthreads();
    if (t == 0) out[0] = (wsum[0] + wsum[1] + wsum[2] + wsum[3]) / 128.0f;
}

extern "C" void kernel_launch(void* const* d_in, const int* in_sizes, int n_in,
                              void* d_out, int out_size, void* d_ws, size_t ws_size,
                              hipStream_t stream) {
    const float* z = (const float*)d_in[1];       // semantic_embeddings
    const int* labels = (const int*)d_in[3];      // labels

    ushort* zn = (ushort*)d_ws;                                   // 16 MB bf16
    char* p = (char*)d_ws + (size_t)N_ROWS * DIM * 2;
    float* row_same = (float*)p;                 p += N_ROWS * sizeof(float);
    float* row_diff = (float*)p;                 p += N_ROWS * sizeof(float);
    float* cls_same = (float*)p;                 p += 256 * sizeof(float);
    float* cls_diff = (float*)p;                 p += 256 * sizeof(float);
    int*   cls_cnt  = (int*)p;

    hipMemsetAsync(row_same, 0,
                   (2 * N_ROWS + 2 * 256) * sizeof(float) + 256 * sizeof(int),
                   stream);

    normalize_kernel<<<N_ROWS / 4, 256, 0, stream>>>(z, zn);

    gram_kernel<<<GRIDB, 256, 0, stream>>>(zn, labels, row_same, row_diff);

    class_sum_kernel<<<N_ROWS / 256, 256, 0, stream>>>(labels, row_same, row_diff,
                                                       cls_same, cls_diff, cls_cnt);
    final_kernel<<<1, 256, 0, stream>>>(cls_same, cls_diff, cls_cnt, (float*)d_out);
}